// Round 3
// baseline (731.262 us; speedup 1.0000x reference)
//
#include <hip/hip_runtime.h>

#define N_BINS 15

typedef float f32x4 __attribute__((ext_vector_type(4)));

__device__ __forceinline__ f32x4 ntld(const void* p) {
    return __builtin_nontemporal_load((const f32x4*)p);
}

// d_ws layout: [0..14] sum_conf, [15..29] sum_acc, [30..44] count  (floats)
// [64..108]: scratch bins for the timing-probe pass (never read)

__global__ __launch_bounds__(256) void ece_main(const float* __restrict__ probs,
                                                const int* __restrict__ labels,
                                                float* __restrict__ gbins, int N) {
    __shared__ float s_bins[3 * N_BINS];
    const int tid = threadIdx.x;
    if (tid < 3 * N_BINS) s_bins[tid] = 0.f;
    __syncthreads();

    const int lane = tid & 63;
    const int wave = tid >> 6;
    const int l4   = lane & 3;    // which 16B sub-chunk of each 64B chunk this lane reads
    const int rsub = lane >> 2;   // which of the wave's 16 rows (per group) this lane helps
    const int wavesPerBlock = blockDim.x >> 6;

    // private accumulators (bin14 ~98.8% of rows, bin13 ~1.2%)
    float c14 = 0.f, a14 = 0.f, n14 = 0.f;
    float c13 = 0.f, a13 = 0.f, n13 = 0.f;

    const unsigned Nu = (unsigned)N;
    const unsigned totalWaves = (unsigned)gridDim.x * wavesPerBlock;
    const unsigned stride = totalWaves * 32u;              // 32 rows per wave per iter
    unsigned rbase = ((unsigned)blockIdx.x * wavesPerBlock + wave) * 32u;
    const char* pb = (const char*)probs;

    // process one 16-row group held in registers; rows are lane-parallel (4 lanes/row)
    auto doGroup = [&](f32x4 v0, f32x4 v1, f32x4 v2, f32x4 v3, int lab, bool valid) {
        // max over this lane's 16 elements — pure max tree (fuses to v_max3)
        const float m0 = fmaxf(fmaxf(v0.x, v0.y), fmaxf(v0.z, v0.w));
        const float m1 = fmaxf(fmaxf(v1.x, v1.y), fmaxf(v1.z, v1.w));
        const float m2 = fmaxf(fmaxf(v2.x, v2.y), fmaxf(v2.z, v2.w));
        const float m3 = fmaxf(fmaxf(v3.x, v3.y), fmaxf(v3.z, v3.w));
        const float m  = fmaxf(fmaxf(m0, m1), fmaxf(m2, m3));

        // value at the label column (no argmax needed: acc = (probs[row][lab] == max))
        const int c2 = (lab >> 4) & 3;
        const int k2 = lab & 3;
        const int ow = (lab >> 2) & 3;
        const f32x4 cc = (c2 & 2) ? ((c2 & 1) ? v3 : v2) : ((c2 & 1) ? v1 : v0);
        const float e = (k2 & 2) ? ((k2 & 1) ? cc.w : cc.z)
                                 : ((k2 & 1) ? cc.y : cc.x);

        float conf = valid ? m : -1.f;
        float lv   = (valid && ow == l4) ? e : -1.f;

        // 2-step butterfly across the row's 4 lanes: max for both conf and label-value
        #pragma unroll
        for (int off = 1; off <= 2; off <<= 1) {
            conf = fmaxf(conf, __shfl_xor(conf, off, 64));
            lv   = fmaxf(lv,   __shfl_xor(lv,   off, 64));
        }

        if (l4 == 0 && valid && conf > 0.f) {
            const float acc = (lv == conf) ? 1.f : 0.f;
            int bin = (int)ceilf(conf * 15.f) - 1;          // (lower, upper] bins
            bin = min(max(bin, 0), N_BINS - 1);
            if (bin == 14)      { c14 += conf; a14 += acc; n14 += 1.f; }
            else if (bin == 13) { c13 += conf; a13 += acc; n13 += 1.f; }
            else {                                           // ~1e-4 of rows
                atomicAdd(&s_bins[bin],              conf);
                atomicAdd(&s_bins[N_BINS + bin],     acc);
                atomicAdd(&s_bins[2 * N_BINS + bin], 1.f);
            }
        }
    };

    for (; rbase < Nu; rbase += stride) {                   // wave-uniform bound
        const unsigned rowA = rbase + rsub;
        const unsigned rowB = rowA + 16u;
        const bool vA = rowA < Nu;
        const bool vB = rowB < Nu;
        const unsigned rAc = vA ? rowA : (Nu - 1u);         // clamp: loads always safe
        const unsigned rBc = vB ? rowB : (Nu - 1u);

        const char* pA = pb + (rAc * 256u + (unsigned)l4 * 16u);
        const char* pB = pb + (rBc * 256u + (unsigned)l4 * 16u);

        // 8 independent non-temporal 16B loads issued back-to-back
        const f32x4 a0 = ntld(pA);
        const f32x4 a1 = ntld(pA + 64);
        const f32x4 a2 = ntld(pA + 128);
        const f32x4 a3 = ntld(pA + 192);
        const f32x4 b0 = ntld(pB);
        const f32x4 b1 = ntld(pB + 64);
        const f32x4 b2 = ntld(pB + 128);
        const f32x4 b3 = ntld(pB + 192);
        const int labA = labels[rAc];
        const int labB = labels[rBc];

        doGroup(a0, a1, a2, a3, labA, vA);
        doGroup(b0, b1, b2, b3, labB, vB);
    }

    // privates are nonzero only on l4==0 lanes (0,4,...,60) → butterfly to lane 0
    #pragma unroll
    for (int off = 4; off <= 32; off <<= 1) {
        c14 += __shfl_xor(c14, off, 64);
        a14 += __shfl_xor(a14, off, 64);
        n14 += __shfl_xor(n14, off, 64);
        c13 += __shfl_xor(c13, off, 64);
        a13 += __shfl_xor(a13, off, 64);
        n13 += __shfl_xor(n13, off, 64);
    }
    if (lane == 0) {
        atomicAdd(&s_bins[14],              c14);
        atomicAdd(&s_bins[N_BINS + 14],     a14);
        atomicAdd(&s_bins[2 * N_BINS + 14], n14);
        atomicAdd(&s_bins[13],              c13);
        atomicAdd(&s_bins[N_BINS + 13],     a13);
        atomicAdd(&s_bins[2 * N_BINS + 13], n13);
    }
    __syncthreads();
    // flush only nonzero bins → ~6 instead of 45 global atomics per block
    if (tid < 3 * N_BINS && s_bins[tid] != 0.f) atomicAdd(&gbins[tid], s_bins[tid]);
}

__global__ void ece_final(const float* __restrict__ gbins,
                          float* __restrict__ out, int N) {
    if (threadIdx.x == 0 && blockIdx.x == 0) {
        float ece = 0.f;
        const float invN = 1.f / (float)N;
        for (int b = 0; b < N_BINS; b++) {
            const float sc = gbins[b];
            const float sa = gbins[N_BINS + b];
            const float cn = gbins[2 * N_BINS + b];
            if (cn > 0.f) {
                const float avg_conf = sc / cn;
                const float avg_acc  = sa / cn;
                ece += fabsf(avg_conf - avg_acc) * (cn * invN);
            }
        }
        out[0] = ece;
    }
}

extern "C" void kernel_launch(void* const* d_in, const int* in_sizes, int n_in,
                              void* d_out, int out_size, void* d_ws, size_t ws_size,
                              hipStream_t stream) {
    const float* probs  = (const float*)d_in[0];
    const int*   labels = (const int*)d_in[1];
    float* gbins = (float*)d_ws;
    float* out   = (float*)d_out;

    const int N = in_sizes[1];   // number of rows (labels count)

    hipMemsetAsync(d_ws, 0, 3 * N_BINS * sizeof(float), stream);

    const int threads = 256;     // 4 waves/block
    const int blocks  = 2048;    // 8192 waves

    // TIMING PROBE (round 3): byte-identical extra pass into scratch bins.
    // Δdur vs round 2 measures one full steady-state pass over probs.
    // Results are accumulated at ws[64..108] and never read.
    ece_main<<<blocks, threads, 0, stream>>>(probs, labels, gbins + 64, N);

    ece_main<<<blocks, threads, 0, stream>>>(probs, labels, gbins, N);
    ece_final<<<1, 64, 0, stream>>>(gbins, out, N);
}

// Round 4
// 640.608 us; speedup vs baseline: 1.1415x; 1.1415x over previous
//
#include <hip/hip_runtime.h>

#define N_BINS 15

typedef float f32x4 __attribute__((ext_vector_type(4)));

__device__ __forceinline__ f32x4 ntld(const void* p) {
    return __builtin_nontemporal_load((const f32x4*)p);
}

// d_ws layout: [0..14] sum_conf, [15..29] sum_acc, [30..44] count  (floats)
//
// ROOFLINE NOTE (round-3 duplicate-launch probe): one full ece_main pass over
// probs+labels measures 86.5 µs = ~6.0 TB/s, vs 81 µs ideal at the 6.4 TB/s
// this chip's own 2 GB fills achieve. The kernel is at the HBM streaming
// floor; the rest of dur_us (~558 µs) is harness-fixed fill/restore traffic.

__global__ __launch_bounds__(256) void ece_main(const float* __restrict__ probs,
                                                const int* __restrict__ labels,
                                                float* __restrict__ gbins, int N) {
    __shared__ float s_bins[3 * N_BINS];
    const int tid = threadIdx.x;
    if (tid < 3 * N_BINS) s_bins[tid] = 0.f;
    __syncthreads();

    const int lane = tid & 63;
    const int wave = tid >> 6;
    const int l4   = lane & 3;    // which 16B sub-chunk of each 64B chunk this lane reads
    const int rsub = lane >> 2;   // which of the wave's 16 rows (per group) this lane helps
    const int wavesPerBlock = blockDim.x >> 6;

    // private accumulators (bin14 ~98.8% of rows, bin13 ~1.2%)
    float c14 = 0.f, a14 = 0.f, n14 = 0.f;
    float c13 = 0.f, a13 = 0.f, n13 = 0.f;

    const unsigned Nu = (unsigned)N;
    const unsigned totalWaves = (unsigned)gridDim.x * wavesPerBlock;
    const unsigned stride = totalWaves * 32u;              // 32 rows per wave per iter
    unsigned rbase = ((unsigned)blockIdx.x * wavesPerBlock + wave) * 32u;
    const char* pb = (const char*)probs;

    // process one 16-row group held in registers; rows are lane-parallel (4 lanes/row)
    auto doGroup = [&](f32x4 v0, f32x4 v1, f32x4 v2, f32x4 v3, int lab, bool valid) {
        // max over this lane's 16 elements — pure max tree (fuses to v_max3)
        const float m0 = fmaxf(fmaxf(v0.x, v0.y), fmaxf(v0.z, v0.w));
        const float m1 = fmaxf(fmaxf(v1.x, v1.y), fmaxf(v1.z, v1.w));
        const float m2 = fmaxf(fmaxf(v2.x, v2.y), fmaxf(v2.z, v2.w));
        const float m3 = fmaxf(fmaxf(v3.x, v3.y), fmaxf(v3.z, v3.w));
        const float m  = fmaxf(fmaxf(m0, m1), fmaxf(m2, m3));

        // value at the label column (no argmax needed: acc = (probs[row][lab] == max))
        const int c2 = (lab >> 4) & 3;
        const int k2 = lab & 3;
        const int ow = (lab >> 2) & 3;
        const f32x4 cc = (c2 & 2) ? ((c2 & 1) ? v3 : v2) : ((c2 & 1) ? v1 : v0);
        const float e = (k2 & 2) ? ((k2 & 1) ? cc.w : cc.z)
                                 : ((k2 & 1) ? cc.y : cc.x);

        float conf = valid ? m : -1.f;
        float lv   = (valid && ow == l4) ? e : -1.f;

        // 2-step butterfly across the row's 4 lanes: max for both conf and label-value
        #pragma unroll
        for (int off = 1; off <= 2; off <<= 1) {
            conf = fmaxf(conf, __shfl_xor(conf, off, 64));
            lv   = fmaxf(lv,   __shfl_xor(lv,   off, 64));
        }

        if (l4 == 0 && valid && conf > 0.f) {
            const float acc = (lv == conf) ? 1.f : 0.f;
            int bin = (int)ceilf(conf * 15.f) - 1;          // (lower, upper] bins
            bin = min(max(bin, 0), N_BINS - 1);
            if (bin == 14)      { c14 += conf; a14 += acc; n14 += 1.f; }
            else if (bin == 13) { c13 += conf; a13 += acc; n13 += 1.f; }
            else {                                           // ~1e-4 of rows
                atomicAdd(&s_bins[bin],              conf);
                atomicAdd(&s_bins[N_BINS + bin],     acc);
                atomicAdd(&s_bins[2 * N_BINS + bin], 1.f);
            }
        }
    };

    for (; rbase < Nu; rbase += stride) {                   // wave-uniform bound
        const unsigned rowA = rbase + rsub;
        const unsigned rowB = rowA + 16u;
        const bool vA = rowA < Nu;
        const bool vB = rowB < Nu;
        const unsigned rAc = vA ? rowA : (Nu - 1u);         // clamp: loads always safe
        const unsigned rBc = vB ? rowB : (Nu - 1u);

        const char* pA = pb + (rAc * 256u + (unsigned)l4 * 16u);
        const char* pB = pb + (rBc * 256u + (unsigned)l4 * 16u);

        // 8 independent non-temporal 16B loads issued back-to-back
        const f32x4 a0 = ntld(pA);
        const f32x4 a1 = ntld(pA + 64);
        const f32x4 a2 = ntld(pA + 128);
        const f32x4 a3 = ntld(pA + 192);
        const f32x4 b0 = ntld(pB);
        const f32x4 b1 = ntld(pB + 64);
        const f32x4 b2 = ntld(pB + 128);
        const f32x4 b3 = ntld(pB + 192);
        const int labA = labels[rAc];
        const int labB = labels[rBc];

        doGroup(a0, a1, a2, a3, labA, vA);
        doGroup(b0, b1, b2, b3, labB, vB);
    }

    // privates are nonzero only on l4==0 lanes (0,4,...,60) → butterfly to lane 0
    #pragma unroll
    for (int off = 4; off <= 32; off <<= 1) {
        c14 += __shfl_xor(c14, off, 64);
        a14 += __shfl_xor(a14, off, 64);
        n14 += __shfl_xor(n14, off, 64);
        c13 += __shfl_xor(c13, off, 64);
        a13 += __shfl_xor(a13, off, 64);
        n13 += __shfl_xor(n13, off, 64);
    }
    if (lane == 0) {
        atomicAdd(&s_bins[14],              c14);
        atomicAdd(&s_bins[N_BINS + 14],     a14);
        atomicAdd(&s_bins[2 * N_BINS + 14], n14);
        atomicAdd(&s_bins[13],              c13);
        atomicAdd(&s_bins[N_BINS + 13],     a13);
        atomicAdd(&s_bins[2 * N_BINS + 13], n13);
    }
    __syncthreads();
    // flush only nonzero bins → ~6 instead of 45 global atomics per block
    if (tid < 3 * N_BINS && s_bins[tid] != 0.f) atomicAdd(&gbins[tid], s_bins[tid]);
}

__global__ void ece_final(const float* __restrict__ gbins,
                          float* __restrict__ out, int N) {
    if (threadIdx.x == 0 && blockIdx.x == 0) {
        float ece = 0.f;
        const float invN = 1.f / (float)N;
        for (int b = 0; b < N_BINS; b++) {
            const float sc = gbins[b];
            const float sa = gbins[N_BINS + b];
            const float cn = gbins[2 * N_BINS + b];
            if (cn > 0.f) {
                const float avg_conf = sc / cn;
                const float avg_acc  = sa / cn;
                ece += fabsf(avg_conf - avg_acc) * (cn * invN);
            }
        }
        out[0] = ece;
    }
}

extern "C" void kernel_launch(void* const* d_in, const int* in_sizes, int n_in,
                              void* d_out, int out_size, void* d_ws, size_t ws_size,
                              hipStream_t stream) {
    const float* probs  = (const float*)d_in[0];
    const int*   labels = (const int*)d_in[1];
    float* gbins = (float*)d_ws;
    float* out   = (float*)d_out;

    const int N = in_sizes[1];   // number of rows (labels count)

    hipMemsetAsync(d_ws, 0, 3 * N_BINS * sizeof(float), stream);

    const int threads = 256;     // 4 waves/block
    const int blocks  = 2048;    // 8192 waves
    ece_main<<<blocks, threads, 0, stream>>>(probs, labels, gbins, N);
    ece_final<<<1, 64, 0, stream>>>(gbins, out, N);
}